// Round 1
// baseline (215.348 us; speedup 1.0000x reference)
//
#include <hip/hip_runtime.h>
#include <math.h>

#define B_  32
#define N_  256
#define K_  8
#define HW_ 196
#define C_  1000
#define D_  50176            // N_*HW_
#define WK_ 12845056         // N_*N_*HW_ per k

// ws float offsets
#define WS_LOGITS 0
#define WS_AH     50176      // B*K*HW
#define WS_DR     100352     // B*K*N  (65536 floats)

// ---------------- kernel A: logits (1x1 conv) + zero dr accumulator ----------------
__global__ __launch_bounds__(256) void k_logits(const float* __restrict__ x,
                                                const float* __restrict__ cw,
                                                float* __restrict__ ws) {
  const int b = blockIdx.x, k = blockIdx.y;
  const int t = threadIdx.x;
  __shared__ float cwl[N_];
  cwl[t] = cw[k*N_ + t];
  ws[WS_DR + (b*K_ + k)*N_ + t] = 0.f;   // zero dim_red accumulator
  __syncthreads();
  if (t < HW_) {
    const float* xb = x + (size_t)b*D_ + t;
    float acc = 0.f;
#pragma unroll 8
    for (int n = 0; n < N_; ++n) acc = fmaf(xb[(size_t)n*HW_], cwl[n], acc);
    ws[WS_LOGITS + (b*K_ + k)*HW_ + t] = acc;
  }
}

// ---------------- kernel B: softmax over k, write ah, compute loss ----------------
__global__ __launch_bounds__(256) void k_smloss(float* __restrict__ ws,
                                                float* __restrict__ out) {
  const int b = blockIdx.x, t = threadIdx.x;
  __shared__ float AH[K_][HW_ + 4];
  __shared__ float red[256];
  if (t < HW_) {
    float v[K_]; float m = -1e30f;
#pragma unroll
    for (int k = 0; k < K_; ++k) { v[k] = ws[WS_LOGITS + (b*K_ + k)*HW_ + t]; m = fmaxf(m, v[k]); }
    float s = 0.f;
#pragma unroll
    for (int k = 0; k < K_; ++k) { v[k] = __expf(v[k] - m); s += v[k]; }
    const float inv = 1.f / s;
#pragma unroll
    for (int k = 0; k < K_; ++k) {
      const float a = v[k] * inv;
      AH[k][t] = a;
      ws[WS_AH + (b*K_ + k)*HW_ + t] = a;
    }
  }
  __syncthreads();
  float l = 0.f;
  if (t < HW_) {                       // G[w,v] contribution, t -> (w,v)
    const int w = t / 14, v2 = t % 14;
    float g = 0.f;
#pragma unroll
    for (int k = 0; k < K_; ++k)
#pragma unroll
      for (int h = 0; h < 14; ++h)
        g = fmaf(AH[k][h*14 + w], AH[k][h*14 + v2], g);
    l = g * g;
  }
  if (t < 112) {                       // loss2, t -> (k,w)
    const int k = t / 14, w = t % 14;
    float s = 0.f;
#pragma unroll
    for (int h = 0; h < 14; ++h) s += AH[k][h*14 + w];
    l -= s * s;
  }
  red[t] = l;
  __syncthreads();
  for (int s2 = 128; s2 > 0; s2 >>= 1) { if (t < s2) red[t] += red[t + s2]; __syncthreads(); }
  if (t == 0) out[256256 + b] = red[0];
}

// ---------------- kernel C: dim_red GEMM  (dominant, 411 MB of dimred_w) ----------------
// grid (128,8): 128 d-chunks of 392 per k.  128 threads, per-thread 8b x 8m fp32 tile.
#define S_   28
#define PH_  14
#define DCH_ 392
__global__ __launch_bounds__(128) void k_dimred(const float* __restrict__ x,
                                                const float* __restrict__ ah,
                                                const float* __restrict__ dw,
                                                float* __restrict__ dr) {
  const int chunk = blockIdx.x, k = blockIdx.y;
  const int t = threadIdx.x;
  const int lane = t & 63, wv = t >> 6;
  const int tb = lane >> 4;              // 0..3  -> b = tb + 4i
  const int tm = (lane & 15) + wv * 16;  // 0..31 -> m = tm + 32j
  __shared__ float Wl[256][32];          // [m][dd^swz]
  __shared__ float Al[32][32];           // [b][dd^swz]
  float acc[8][8] = {{0.f}};
  const float* Wk = dw + (size_t)k * WK_;
  const int d0 = chunk * DCH_;
  const int wswz = (tm & 7) << 2;        // column swizzle for this thread's W reads

  for (int ph = 0; ph < PH_; ++ph) {
    const int dbase = d0 + ph * S_;
    // stage W: 256 rows x 28 d  = 1792 float4 / 128 threads = 14 each
#pragma unroll
    for (int i = 0; i < 14; ++i) {
      const int j = i*128 + t;
      const int m = j / 7, c = j % 7;
      const float4 v = *(const float4*)(Wk + (size_t)m*D_ + dbase + c*4);
      const int col = (c*4) ^ ((m & 7) << 2);
      *(float4*)&Wl[m][col] = v;
    }
    // stage A = x * ah : 32 b x 28 d = 224 float4
#pragma unroll
    for (int i = 0; i < 2; ++i) {
      const int e = i*128 + t;
      if (e < 224) {
        const int b = e / 7, c = e % 7;
        const int d = dbase + c*4;
        const float4 xv = *(const float4*)(x + (size_t)b*D_ + d);
        const float* ahb = ah + (b*K_ + k)*HW_;
        float4 av;
        av.x = xv.x * ahb[(d+0) % HW_];
        av.y = xv.y * ahb[(d+1) % HW_];
        av.z = xv.z * ahb[(d+2) % HW_];
        av.w = xv.w * ahb[(d+3) % HW_];
        const int col = (c*4) ^ ((b & 7) << 2);
        *(float4*)&Al[b][col] = av;
      }
    }
    __syncthreads();
    for (int q = 0; q < 7; ++q) {
      const int dq = q*4;
      float4 a4[8], w4[8];
#pragma unroll
      for (int i = 0; i < 8; ++i) {
        const int bb = tb + 4*i;
        a4[i] = *(const float4*)&Al[bb][dq ^ ((bb & 7) << 2)];
      }
#pragma unroll
      for (int j = 0; j < 8; ++j) {
        const int mm = tm + 32*j;
        w4[j] = *(const float4*)&Wl[mm][dq ^ wswz];
      }
#pragma unroll
      for (int i = 0; i < 8; ++i)
#pragma unroll
        for (int j = 0; j < 8; ++j) {
          acc[i][j] = fmaf(a4[i].x, w4[j].x, acc[i][j]);
          acc[i][j] = fmaf(a4[i].y, w4[j].y, acc[i][j]);
          acc[i][j] = fmaf(a4[i].z, w4[j].z, acc[i][j]);
          acc[i][j] = fmaf(a4[i].w, w4[j].w, acc[i][j]);
        }
    }
    __syncthreads();
  }
#pragma unroll
  for (int i = 0; i < 8; ++i) {
    const int bb = tb + 4*i;
#pragma unroll
    for (int j = 0; j < 8; ++j) {
      const int mm = tm + 32*j;
      atomicAdd(&dr[(bb*K_ + k)*N_ + mm], acc[i][j]);
    }
  }
}

// ---------------- kernel D: hyp = dr@Wo^T + b ; conf = tanh(dr@Wg + b) ----------------
// grid (32,8): ct covers 32 c's, k.  256 threads = 32 c x 8 b-groups(4 b via float4).
__global__ __launch_bounds__(256) void k_out(const float* __restrict__ dr,
                                             const float* __restrict__ db,
                                             const float* __restrict__ Wo,
                                             const float* __restrict__ Wob,
                                             const float* __restrict__ Wg,
                                             const float* __restrict__ Wgb,
                                             float* __restrict__ out) {
  const int ct = blockIdx.x, k = blockIdx.y;
  const int t = threadIdx.x;
  __shared__ float Wl[32][257];
  __shared__ float dl[256][36];   // [n][b], padded for b128
#pragma unroll
  for (int i = 0; i < 32; ++i) {
    const int e = i*256 + t;
    const int row = e >> 8, col = e & 255;
    const int c = ct*32 + row;
    Wl[row][col] = (c < C_) ? Wo[((size_t)(k*C_ + c))*N_ + col] : 0.f;
  }
#pragma unroll
  for (int i = 0; i < 32; ++i) {
    const int e = i*256 + t;
    const int n = e & 255, b = e >> 8;
    dl[n][b] = dr[(b*K_ + k)*N_ + n] + db[k*N_ + n];
  }
  __syncthreads();
  const int tc = t & 31, tg = t >> 5;
  const int c = ct*32 + tc;
  float a0=0.f, a1=0.f, a2=0.f, a3=0.f;
#pragma unroll 8
  for (int n = 0; n < N_; ++n) {
    const float wvv = Wl[tc][n];
    const float4 dv = *(const float4*)&dl[n][tg*4];
    a0 = fmaf(wvv, dv.x, a0);
    a1 = fmaf(wvv, dv.y, a1);
    a2 = fmaf(wvv, dv.z, a2);
    a3 = fmaf(wvv, dv.w, a3);
  }
  if (c < C_) {
    const float bias = Wob[k*C_ + c];
    out[((size_t)(tg*4 + 0)*K_ + k)*C_ + c] = a0 + bias;
    out[((size_t)(tg*4 + 1)*K_ + k)*C_ + c] = a1 + bias;
    out[((size_t)(tg*4 + 2)*K_ + k)*C_ + c] = a2 + bias;
    out[((size_t)(tg*4 + 3)*K_ + k)*C_ + c] = a3 + bias;
  }
  if (ct == 0 && t < B_) {   // conf
    float s = Wgb[k];
    for (int n = 0; n < N_; ++n) s = fmaf(dl[n][t], Wg[k*N_ + n], s);
    out[256000 + t*K_ + k] = tanhf(s);
  }
}

extern "C" void kernel_launch(void* const* d_in, const int* in_sizes, int n_in,
                              void* d_out, int out_size, void* d_ws, size_t ws_size,
                              hipStream_t stream) {
  const float* x   = (const float*)d_in[0];
  const float* cw  = (const float*)d_in[1];
  const float* dw  = (const float*)d_in[2];
  const float* db  = (const float*)d_in[3];
  const float* Wo  = (const float*)d_in[4];
  const float* Wob = (const float*)d_in[5];
  const float* Wg  = (const float*)d_in[6];
  const float* Wgb = (const float*)d_in[7];
  float* out = (float*)d_out;
  float* ws  = (float*)d_ws;

  k_logits<<<dim3(32, 8), 256, 0, stream>>>(x, cw, ws);
  k_smloss<<<32, 256, 0, stream>>>(ws, out);
  k_dimred<<<dim3(128, 8), 128, 0, stream>>>(x, ws + WS_AH, dw, ws + WS_DR);
  k_out<<<dim3(32, 8), 256, 0, stream>>>(ws + WS_DR, db, Wo, Wob, Wg, Wgb, out);
}